// Round 9
// baseline (283.238 us; speedup 1.0000x reference)
//
#include <hip/hip_runtime.h>
#include <cstdint>
#include <cstddef>

namespace {

constexpr int B = 8, NSEQ = 1024, C = 768, H = 12, D = 64, N3 = 2304;
constexpr float SCALE = 0.125f;
constexpr size_t QKV_ELEMS = (size_t)B * H * NSEQ * D;   // 6291456 per tensor

using f32x4 = __attribute__((ext_vector_type(4))) float;
using s16x8 = __attribute__((ext_vector_type(8))) short;

__device__ __forceinline__ unsigned short f2bf(float f) {
  union { float f; uint32_t u; } v; v.f = f;
  const uint32_t r = v.u + 0x7FFFu + ((v.u >> 16) & 1u);   // RNE
  return (unsigned short)(r >> 16);
}
__device__ __forceinline__ float bf2f(unsigned short s) {
  union { uint32_t u; float f; } v; v.u = ((uint32_t)s) << 16;
  return v.f;
}
__device__ __forceinline__ void gload_lds16(const void* g, void* l) {
  __builtin_amdgcn_global_load_lds(
      (const __attribute__((address_space(1))) uint32_t*)g,
      (__attribute__((address_space(3))) uint32_t*)l, 16, 0, 0);
}

// ---------------------------------------------------------------------------
// x -> bf16
// ---------------------------------------------------------------------------
__global__ __launch_bounds__(256)
void cvt_x(const float* __restrict__ x, unsigned short* __restrict__ xb, int n4) {
  const int stride = gridDim.x * 256;
  for (int idx = blockIdx.x * 256 + threadIdx.x; idx < n4; idx += stride) {
    const float4 v = ((const float4*)x)[idx];
    ushort4 o;
    o.x = f2bf(v.x); o.y = f2bf(v.y); o.z = f2bf(v.z); o.w = f2bf(v.w);
    ((ushort4*)xb)[idx] = o;
  }
}

// ---------------------------------------------------------------------------
// W[K][N] fp32 -> Wt[N][K] bf16
// ---------------------------------------------------------------------------
__global__ __launch_bounds__(256)
void transp_cvt(const float* __restrict__ w, unsigned short* __restrict__ wt,
                int K, int N) {
  __shared__ float t[32][33];
  const int n0 = blockIdx.x << 5, k0 = blockIdx.y << 5;
  const int tid = threadIdx.x;
  #pragma unroll
  for (int r = 0; r < 4; ++r) {
    const int e = (r << 8) + tid;
    const int kk = e >> 5, nn = e & 31;
    t[kk][nn] = w[(size_t)(k0 + kk) * N + n0 + nn];
  }
  __syncthreads();
  #pragma unroll
  for (int r = 0; r < 4; ++r) {
    const int e = (r << 8) + tid;
    const int nn = e >> 5, kk = e & 31;
    wt[(size_t)(n0 + nn) * K + k0 + kk] = f2bf(t[kk][nn]);
  }
}

// ---------------------------------------------------------------------------
// bf16 MFMA GEMM: out = A[M][768] @ Wt[N][768]^T + bias  (unchanged)
// ---------------------------------------------------------------------------
template<int MODE>
__global__ __launch_bounds__(256, 2)
void gemm_bf16(const unsigned short* __restrict__ A,
               const unsigned short* __restrict__ Wt,
               const float* __restrict__ bias,
               unsigned short* __restrict__ qp, unsigned short* __restrict__ kp,
               unsigned short* __restrict__ vt, float* __restrict__ out32,
               int N, int NT) {
  constexpr int K = 768;
  __shared__ short As[128 * 64];
  __shared__ short Bs[128 * 64];
  const int tid = threadIdx.x;
  const int wid = tid >> 6, lane = tid & 63;
  const int wm = wid >> 1, wn = wid & 1;
  const int lg = lane >> 4, lr = lane & 15;

  const int cpx = gridDim.x >> 3;
  const int logical = (blockIdx.x & 7) * cpx + (blockIdx.x >> 3);
  const int bx = logical % NT, by = logical / NT;
  const int m0 = by << 7, n0 = bx << 7;

  f32x4 acc[4][4] = {};

  for (int k0 = 0; k0 < K; k0 += 64) {
    __syncthreads();
    #pragma unroll
    for (int r = 0; r < 4; ++r) {
      const int c = (r << 8) + tid;
      const int row = c >> 3, g8 = c & 7;
      const int gp = g8 ^ (row & 7);
      const int ldsoff = (((r << 8) + (wid << 6)) << 3);
      gload_lds16(A + (size_t)(m0 + row) * K + k0 + (gp << 3), (void*)(As + ldsoff));
      gload_lds16(Wt + (size_t)(n0 + row) * K + k0 + (gp << 3), (void*)(Bs + ldsoff));
    }
    __syncthreads();
    #pragma unroll
    for (int kc = 0; kc < 2; ++kc) {
      s16x8 af[4], bf[4];
      #pragma unroll
      for (int i = 0; i < 4; ++i) {
        const int ra = (wm << 6) + (i << 4) + lr;
        const int ca = ((kc << 2) + lg) ^ (ra & 7);
        af[i] = *(const s16x8*)(As + (ra << 6) + (ca << 3));
        const int rb = (wn << 6) + (i << 4) + lr;
        const int cb = ((kc << 2) + lg) ^ (rb & 7);
        bf[i] = *(const s16x8*)(Bs + (rb << 6) + (cb << 3));
      }
      #pragma unroll
      for (int i = 0; i < 4; ++i)
        #pragma unroll
        for (int j = 0; j < 4; ++j)
          acc[i][j] = __builtin_amdgcn_mfma_f32_16x16x32_bf16(af[i], bf[j], acc[i][j], 0, 0, 0);
    }
  }

  #pragma unroll
  for (int i = 0; i < 4; ++i) {
    const int m = m0 + (wm << 6) + (i << 4) + (lg << 2);
    #pragma unroll
    for (int j = 0; j < 4; ++j) {
      const int n = n0 + (wn << 6) + (j << 4) + lr;
      const float bv = bias[n];
      if (MODE == 0) {
        const int which = (n >= 1536) ? 2 : (n >= 768 ? 1 : 0);
        const int hh = (n - which * 768) >> 6;
        const int d = n & 63;
        const int b = m >> 10, ns = m & 1023;
        const size_t bh = (size_t)b * H + hh;
        if (which < 2) {
          unsigned short* dst = (which == 0 ? qp : kp) + (bh * NSEQ + ns) * D + d;
          #pragma unroll
          for (int rg = 0; rg < 4; ++rg)
            dst[(size_t)rg * D] = f2bf(acc[i][j][rg] + bv);
        } else {
          ushort4 pk;
          pk.x = f2bf(acc[i][j][0] + bv);
          pk.y = f2bf(acc[i][j][1] + bv);
          pk.z = f2bf(acc[i][j][2] + bv);
          pk.w = f2bf(acc[i][j][3] + bv);
          *(ushort4*)(vt + (bh * D + d) * NSEQ + ns) = pk;
        }
      } else {
        float* dst = out32 + (size_t)m * N + n;
        #pragma unroll
        for (int rg = 0; rg < 4; ++rg)
          dst[(size_t)rg * N] = acc[i][j][rg] + bv;
      }
    }
  }
}

// ---------------------------------------------------------------------------
// Attention v6 = R8 + software-pipelined PV (depth-2 V prefetch).
// vmcnt poisoning fix: V(t) is always ISSUED before S(t-1) (in-order vmcnt
// retirement means the wait for V(t) then only covers stores <= S(t-3),
// which are long retired) -> PV never stalls on the 402MB attnw store drain,
// while stores still flow throughout the PV phase (duty cycle).
// ---------------------------------------------------------------------------
constexpr int RS = 1032;   // shorts per score row (16B-aligned rows)

__device__ __forceinline__ int scidx(int q, int col) {
  return q * RS + ((((col >> 3) ^ (q & 7)) << 3) | (col & 7));
}

__global__ __launch_bounds__(512, 4)
void attn_mfma(const unsigned short* __restrict__ qg,
               const unsigned short* __restrict__ kg,
               const unsigned short* __restrict__ vtg,
               float* __restrict__ attnw,
               unsigned short* __restrict__ aout) {
  __shared__ __align__(16) short sc[32 * RS];
  __shared__ float invs[32];
  const int tid = threadIdx.x;
  const int wid = tid >> 6, lane = tid & 63;
  const int lg = lane >> 4, lr = lane & 15;
  const int wq = wid >> 2, ws = wid & 3;

  // bijective XCD swizzle: 3072 blocks -> 384/XCD -> 12 heads/XCD (K/V L2-hot)
  const int logical = (blockIdx.x & 7) * 384 + (blockIdx.x >> 3);
  const int bh = logical >> 5;
  const int q0 = (logical & 31) << 5;
  const size_t kvbase = (size_t)bh * NSEQ * D;

  // Q B-frags: lane serves q-col = wq*16 + lr, k-slice kc*32 + lg*8
  s16x8 qf[2];
  #pragma unroll
  for (int kc = 0; kc < 2; ++kc)
    qf[kc] = *(const s16x8*)(qg + kvbase + (size_t)(q0 + (wq << 4) + lr) * D + (kc << 5) + (lg << 3));

  // ---- QK^T (swapped): 16 independent tiles, zero barriers ----
  {
    const unsigned short* kptr = kg + kvbase + (size_t)((ws << 4) + lr) * D + (lg << 3);
    const int qloc = (wq << 4) + lr;
    #pragma unroll 4
    for (int t = 0; t < 16; ++t) {
      f32x4 acc = {};
      #pragma unroll
      for (int kc = 0; kc < 2; ++kc) {
        const s16x8 kf = *(const s16x8*)(kptr + t * 64 * D + (kc << 5));
        acc = __builtin_amdgcn_mfma_f32_16x16x32_bf16(kf, qf[kc], acc, 0, 0, 0);
      }
      ushort4 pk;
      pk.x = f2bf(acc[0] * SCALE); pk.y = f2bf(acc[1] * SCALE);
      pk.z = f2bf(acc[2] * SCALE); pk.w = f2bf(acc[3] * SCALE);
      *(ushort4*)(sc + scidx(qloc, (t << 6) + (ws << 4) + (lg << 2))) = pk;
    }
  }
  __syncthreads();

  // ---- softmax: each 16-thread group owns one row ----
  {
    const int row = tid >> 4, ql = tid & 15;
    const int rx = row & 7;
    float mx = -3.0e38f;
    #pragma unroll
    for (int c = 0; c < 8; ++c) {
      const s16x8 v = *(const s16x8*)(sc + row * RS + (((ql + (c << 4)) ^ rx) << 3));
      #pragma unroll
      for (int e = 0; e < 8; ++e) mx = fmaxf(mx, bf2f((unsigned short)v[e]));
    }
    #pragma unroll
    for (int off = 8; off > 0; off >>= 1) mx = fmaxf(mx, __shfl_xor(mx, off, 16));
    float s = 0.f;
    #pragma unroll
    for (int c = 0; c < 8; ++c) {
      s16x8 v = *(s16x8*)(sc + row * RS + (((ql + (c << 4)) ^ rx) << 3));
      #pragma unroll
      for (int e = 0; e < 8; ++e) {
        const float ev = __expf(bf2f((unsigned short)v[e]) - mx);
        s += ev;
        v[e] = (short)f2bf(ev);
      }
      *(s16x8*)(sc + row * RS + (((ql + (c << 4)) ^ rx) << 3)) = v;
    }
    #pragma unroll
    for (int off = 8; off > 0; off >>= 1) s += __shfl_xor(s, off, 16);
    if (ql == 0) invs[row] = 1.0f / s;
  }
  __syncthreads();

  // ---- PV + interleaved attnw stores, depth-2 V-prefetch pipeline ----
  f32x4 oa0 = {}, oa1 = {};
  {
    const int qrow = (wq << 4) + lr;           // PV A-operand row (local q)
    const int srow = tid >> 4;                 // store row (local q)
    const float sinv = invs[srow];
    const unsigned short* vptr = vtg + ((size_t)bh * D + (ws << 4) + lr) * NSEQ + (lg << 3);
    float* wrow = attnw + ((size_t)bh * NSEQ + q0 + srow) * NSEQ;
    const int qx = qrow & 7;

    // prologue: V frags for t=0 and t=1 (issued before ANY store)
    s16x8 cA = *(const s16x8*)(vptr);
    s16x8 cB = *(const s16x8*)(vptr + 32);
    s16x8 nA = *(const s16x8*)(vptr + 64);
    s16x8 nB = *(const s16x8*)(vptr + 96);

    #pragma unroll
    for (int t = 0; t < 16; ++t) {
      // 1) issue V loads for t+2 FIRST (before this iteration's store)
      const int tp = (t + 2) & 15;             // wrap: last 2 redundant, valid
      const s16x8 fA = *(const s16x8*)(vptr + (tp << 6));
      const s16x8 fB = *(const s16x8*)(vptr + (tp << 6) + 32);
      // 2) PV MFMAs on current frags (loaded 2 iters ago, BEFORE S(t-1))
      const int j0 = t << 6;
      const s16x8 pa0 = *(const s16x8*)(sc + qrow * RS + ((((j0 >> 3) + lg) ^ qx) << 3));
      const s16x8 pa1 = *(const s16x8*)(sc + qrow * RS + ((((j0 >> 3) + 4 + lg) ^ qx) << 3));
      oa0 = __builtin_amdgcn_mfma_f32_16x16x32_bf16(pa0, cA, oa0, 0, 0, 0);
      oa1 = __builtin_amdgcn_mfma_f32_16x16x32_bf16(pa1, cB, oa1, 0, 0, 0);
      // 3) attnw slice store (512 threads cover 32 rows x 64 cols)
      const int scol = j0 + ((tid & 15) << 2);
      const ushort4 e4 = *(const ushort4*)(sc + srow * RS + ((((scol >> 3) ^ (srow & 7)) << 3) | (scol & 7)));
      f32x4 w;
      w[0] = bf2f(e4.x) * sinv; w[1] = bf2f(e4.y) * sinv;
      w[2] = bf2f(e4.z) * sinv; w[3] = bf2f(e4.w) * sinv;
      *(f32x4*)(wrow + scol) = w;
      // 4) rotate pipeline registers (renames after full unroll)
      cA = nA; cB = nB; nA = fA; nB = fB;
    }
  }

  // ---- aout (bf16): O rows q = wq*16+lg*4+rg, col d = ws*16+lr ----
  {
    const int b = bh / H, hh = bh - b * H;
    const int d = (ws << 4) + lr;
    #pragma unroll
    for (int rg = 0; rg < 4; ++rg) {
      const int qi = (wq << 4) + (lg << 2) + rg;
      aout[((size_t)b * NSEQ + q0 + qi) * C + hh * D + d] =
          f2bf((oa0[rg] + oa1[rg]) * invs[qi]);
    }
  }
}

} // namespace

extern "C" void kernel_launch(void* const* d_in, const int* in_sizes, int n_in,
                              void* d_out, int out_size, void* d_ws, size_t ws_size,
                              hipStream_t stream) {
  const float* x      = (const float*)d_in[0];
  const float* qkv_w  = (const float*)d_in[1];
  const float* qkv_b  = (const float*)d_in[2];
  const float* proj_w = (const float*)d_in[3];
  const float* proj_b = (const float*)d_in[4];

  float* out   = (float*)d_out;                      // [8,1024,768] fp32
  float* attnw = out + (size_t)B * NSEQ * C;         // [8,12,1024,1024] fp32

  unsigned short* xb   = (unsigned short*)d_ws;             // [8192][768]
  unsigned short* wtq  = xb   + (size_t)8192 * 768;         // [2304][768]
  unsigned short* wtp  = wtq  + (size_t)2304 * 768;         // [768][768]
  unsigned short* qp   = wtp  + (size_t)768 * 768;          // [96][1024][64]
  unsigned short* kp   = qp   + QKV_ELEMS;
  unsigned short* vtp  = kp   + QKV_ELEMS;                  // [96][64][1024]
  unsigned short* wsao = vtp  + QKV_ELEMS;                  // [8192][768]

  cvt_x<<<1024, 256, 0, stream>>>(x, xb, (int)((size_t)8192 * 768 / 4));
  transp_cvt<<<dim3(N3 / 32, C / 32), 256, 0, stream>>>(qkv_w, wtq, C, N3);
  transp_cvt<<<dim3(C / 32, C / 32), 256, 0, stream>>>(proj_w, wtp, C, C);

  gemm_bf16<0><<<(N3 / 128) * (8192 / 128), 256, 0, stream>>>(
      xb, wtq, qkv_b, qp, kp, vtp, nullptr, N3, N3 / 128);

  attn_mfma<<<(NSEQ / 32) * (B * H), 512, 0, stream>>>(qp, kp, vtp, attnw, wsao);

  gemm_bf16<1><<<(C / 128) * (8192 / 128), 256, 0, stream>>>(
      wsao, wtp, proj_b, nullptr, nullptr, nullptr, out, C, C / 128);
}

// Round 10
// 281.048 us; speedup vs baseline: 1.0078x; 1.0078x over previous
//
#include <hip/hip_runtime.h>
#include <cstdint>
#include <cstddef>

namespace {

constexpr int B = 8, NSEQ = 1024, C = 768, H = 12, D = 64, N3 = 2304;
constexpr float SCALE = 0.125f;
constexpr size_t QKV_ELEMS = (size_t)B * H * NSEQ * D;   // 6291456 per tensor

using f32x4 = __attribute__((ext_vector_type(4))) float;
using s16x8 = __attribute__((ext_vector_type(8))) short;

__device__ __forceinline__ unsigned short f2bf(float f) {
  union { float f; uint32_t u; } v; v.f = f;
  const uint32_t r = v.u + 0x7FFFu + ((v.u >> 16) & 1u);   // RNE
  return (unsigned short)(r >> 16);
}
__device__ __forceinline__ float bf2f(unsigned short s) {
  union { uint32_t u; float f; } v; v.u = ((uint32_t)s) << 16;
  return v.f;
}
__device__ __forceinline__ void gload_lds16(const void* g, void* l) {
  __builtin_amdgcn_global_load_lds(
      (const __attribute__((address_space(1))) uint32_t*)g,
      (__attribute__((address_space(3))) uint32_t*)l, 16, 0, 0);
}

// ---------------------------------------------------------------------------
// x -> bf16
// ---------------------------------------------------------------------------
__global__ __launch_bounds__(256)
void cvt_x(const float* __restrict__ x, unsigned short* __restrict__ xb, int n4) {
  const int stride = gridDim.x * 256;
  for (int idx = blockIdx.x * 256 + threadIdx.x; idx < n4; idx += stride) {
    const float4 v = ((const float4*)x)[idx];
    ushort4 o;
    o.x = f2bf(v.x); o.y = f2bf(v.y); o.z = f2bf(v.z); o.w = f2bf(v.w);
    ((ushort4*)xb)[idx] = o;
  }
}

// ---------------------------------------------------------------------------
// W[K][N] fp32 -> Wt[N][K] bf16
// ---------------------------------------------------------------------------
__global__ __launch_bounds__(256)
void transp_cvt(const float* __restrict__ w, unsigned short* __restrict__ wt,
                int K, int N) {
  __shared__ float t[32][33];
  const int n0 = blockIdx.x << 5, k0 = blockIdx.y << 5;
  const int tid = threadIdx.x;
  #pragma unroll
  for (int r = 0; r < 4; ++r) {
    const int e = (r << 8) + tid;
    const int kk = e >> 5, nn = e & 31;
    t[kk][nn] = w[(size_t)(k0 + kk) * N + n0 + nn];
  }
  __syncthreads();
  #pragma unroll
  for (int r = 0; r < 4; ++r) {
    const int e = (r << 8) + tid;
    const int nn = e >> 5, kk = e & 31;
    wt[(size_t)(n0 + nn) * K + k0 + kk] = f2bf(t[kk][nn]);
  }
}

// ---------------------------------------------------------------------------
// bf16 MFMA GEMM: out = A[M][768] @ Wt[N][768]^T + bias  (unchanged)
// ---------------------------------------------------------------------------
template<int MODE>
__global__ __launch_bounds__(256, 2)
void gemm_bf16(const unsigned short* __restrict__ A,
               const unsigned short* __restrict__ Wt,
               const float* __restrict__ bias,
               unsigned short* __restrict__ qp, unsigned short* __restrict__ kp,
               unsigned short* __restrict__ vt, float* __restrict__ out32,
               int N, int NT) {
  constexpr int K = 768;
  __shared__ short As[128 * 64];
  __shared__ short Bs[128 * 64];
  const int tid = threadIdx.x;
  const int wid = tid >> 6, lane = tid & 63;
  const int wm = wid >> 1, wn = wid & 1;
  const int lg = lane >> 4, lr = lane & 15;

  const int cpx = gridDim.x >> 3;
  const int logical = (blockIdx.x & 7) * cpx + (blockIdx.x >> 3);
  const int bx = logical % NT, by = logical / NT;
  const int m0 = by << 7, n0 = bx << 7;

  f32x4 acc[4][4] = {};

  for (int k0 = 0; k0 < K; k0 += 64) {
    __syncthreads();
    #pragma unroll
    for (int r = 0; r < 4; ++r) {
      const int c = (r << 8) + tid;
      const int row = c >> 3, g8 = c & 7;
      const int gp = g8 ^ (row & 7);
      const int ldsoff = (((r << 8) + (wid << 6)) << 3);
      gload_lds16(A + (size_t)(m0 + row) * K + k0 + (gp << 3), (void*)(As + ldsoff));
      gload_lds16(Wt + (size_t)(n0 + row) * K + k0 + (gp << 3), (void*)(Bs + ldsoff));
    }
    __syncthreads();
    #pragma unroll
    for (int kc = 0; kc < 2; ++kc) {
      s16x8 af[4], bf[4];
      #pragma unroll
      for (int i = 0; i < 4; ++i) {
        const int ra = (wm << 6) + (i << 4) + lr;
        const int ca = ((kc << 2) + lg) ^ (ra & 7);
        af[i] = *(const s16x8*)(As + (ra << 6) + (ca << 3));
        const int rb = (wn << 6) + (i << 4) + lr;
        const int cb = ((kc << 2) + lg) ^ (rb & 7);
        bf[i] = *(const s16x8*)(Bs + (rb << 6) + (cb << 3));
      }
      #pragma unroll
      for (int i = 0; i < 4; ++i)
        #pragma unroll
        for (int j = 0; j < 4; ++j)
          acc[i][j] = __builtin_amdgcn_mfma_f32_16x16x32_bf16(af[i], bf[j], acc[i][j], 0, 0, 0);
    }
  }

  #pragma unroll
  for (int i = 0; i < 4; ++i) {
    const int m = m0 + (wm << 6) + (i << 4) + (lg << 2);
    #pragma unroll
    for (int j = 0; j < 4; ++j) {
      const int n = n0 + (wn << 6) + (j << 4) + lr;
      const float bv = bias[n];
      if (MODE == 0) {
        const int which = (n >= 1536) ? 2 : (n >= 768 ? 1 : 0);
        const int hh = (n - which * 768) >> 6;
        const int d = n & 63;
        const int b = m >> 10, ns = m & 1023;
        const size_t bh = (size_t)b * H + hh;
        if (which < 2) {
          unsigned short* dst = (which == 0 ? qp : kp) + (bh * NSEQ + ns) * D + d;
          #pragma unroll
          for (int rg = 0; rg < 4; ++rg)
            dst[(size_t)rg * D] = f2bf(acc[i][j][rg] + bv);
        } else {
          ushort4 pk;
          pk.x = f2bf(acc[i][j][0] + bv);
          pk.y = f2bf(acc[i][j][1] + bv);
          pk.z = f2bf(acc[i][j][2] + bv);
          pk.w = f2bf(acc[i][j][3] + bv);
          *(ushort4*)(vt + (bh * D + d) * NSEQ + ns) = pk;
        }
      } else {
        float* dst = out32 + (size_t)m * N + n;
        #pragma unroll
        for (int rg = 0; rg < 4; ++rg)
          dst[(size_t)rg * N] = acc[i][j][rg] + bv;
      }
    }
  }
}

// ---------------------------------------------------------------------------
// Attention v7: 16-q blocks, 256 threads (4 waves), 33KB LDS -> 4 blocks/CU.
// Rationale: all R5-R9 variants (2 blocks/CU) plateau ~240us with every pipe
// <30% busy (phase-correlated stalls). 4 independent phase-offset blocks
// per CU decorrelate VALU/VMEM/store phases. Store placement = R2's (best
// measured): right after softmax, before PV.
// QK^T swapped (j-consecutive score frags), chunk-XOR swizzled sc, L2-direct
// K/V frags, 2 barriers total.
// ---------------------------------------------------------------------------
constexpr int RS = 1032;   // shorts per score row

__device__ __forceinline__ int scidx(int q, int col) {
  return q * RS + ((((col >> 3) ^ (q & 7)) << 3) | (col & 7));
}

__global__ __launch_bounds__(256, 4)
void attn_mfma(const unsigned short* __restrict__ qg,
               const unsigned short* __restrict__ kg,
               const unsigned short* __restrict__ vtg,
               float* __restrict__ attnw,
               unsigned short* __restrict__ aout) {
  __shared__ __align__(16) short sc[16 * RS];   // 33KB
  __shared__ float invs[16];
  const int tid = threadIdx.x;
  const int wid = tid >> 6, lane = tid & 63;
  const int lg = lane >> 4, lr = lane & 15;

  // bijective XCD swizzle: 6144 blocks -> 768/XCD -> 12 heads/XCD (K/V L2-hot)
  const int logical = (blockIdx.x & 7) * 768 + (blockIdx.x >> 3);
  const int bh = logical >> 6;
  const int q0 = (logical & 63) << 4;
  const size_t kvbase = (size_t)bh * NSEQ * D;

  // Q B-frags: lane serves q-col = lr (16 rows), k-slice kc*32 + lg*8
  s16x8 qf[2];
  #pragma unroll
  for (int kc = 0; kc < 2; ++kc)
    qf[kc] = *(const s16x8*)(qg + kvbase + (size_t)(q0 + lr) * D + (kc << 5) + (lg << 3));

  // ---- QK^T (swapped): wave wid covers j-subtile wid*16, 16 sweeps ----
  {
    const unsigned short* kptr = kg + kvbase + (size_t)((wid << 4) + lr) * D + (lg << 3);
    #pragma unroll 4
    for (int t = 0; t < 16; ++t) {
      f32x4 acc = {};
      #pragma unroll
      for (int kc = 0; kc < 2; ++kc) {
        const s16x8 kf = *(const s16x8*)(kptr + t * 64 * D + (kc << 5));
        acc = __builtin_amdgcn_mfma_f32_16x16x32_bf16(kf, qf[kc], acc, 0, 0, 0);
      }
      // lane holds S[j = 64t+16wid+4lg+rg][q = lr], j-consecutive
      ushort4 pk;
      pk.x = f2bf(acc[0] * SCALE); pk.y = f2bf(acc[1] * SCALE);
      pk.z = f2bf(acc[2] * SCALE); pk.w = f2bf(acc[3] * SCALE);
      *(ushort4*)(sc + scidx(lr, (t << 6) + (wid << 4) + (lg << 2))) = pk;
    }
  }
  __syncthreads();

  // ---- softmax: each 16-thread group owns one row ----
  {
    const int row = tid >> 4, ql = tid & 15;
    const int rx = row & 7;
    float mx = -3.0e38f;
    #pragma unroll
    for (int c = 0; c < 8; ++c) {
      const s16x8 v = *(const s16x8*)(sc + row * RS + (((ql + (c << 4)) ^ rx) << 3));
      #pragma unroll
      for (int e = 0; e < 8; ++e) mx = fmaxf(mx, bf2f((unsigned short)v[e]));
    }
    #pragma unroll
    for (int off = 8; off > 0; off >>= 1) mx = fmaxf(mx, __shfl_xor(mx, off, 16));
    float s = 0.f;
    #pragma unroll
    for (int c = 0; c < 8; ++c) {
      s16x8 v = *(s16x8*)(sc + row * RS + (((ql + (c << 4)) ^ rx) << 3));
      #pragma unroll
      for (int e = 0; e < 8; ++e) {
        const float ev = __expf(bf2f((unsigned short)v[e]) - mx);
        s += ev;
        v[e] = (short)f2bf(ev);
      }
      *(s16x8*)(sc + row * RS + (((ql + (c << 4)) ^ rx) << 3)) = v;
    }
    #pragma unroll
    for (int off = 8; off > 0; off >>= 1) s += __shfl_xor(s, off, 16);
    if (ql == 0) invs[row] = 1.0f / s;
  }
  __syncthreads();

  // ---- attnw stores: post-softmax, pre-PV (R2 placement) ----
  {
    const int srow = tid >> 4;
    const float sinv = invs[srow];
    float* wrow = attnw + ((size_t)bh * NSEQ + q0 + srow) * NSEQ;
    #pragma unroll 4
    for (int c = 0; c < 16; ++c) {
      const int scol = (c << 6) + ((tid & 15) << 2);
      const ushort4 e4 = *(const ushort4*)(sc + srow * RS + ((((scol >> 3) ^ (srow & 7)) << 3) | (scol & 7)));
      f32x4 w;
      w[0] = bf2f(e4.x) * sinv; w[1] = bf2f(e4.y) * sinv;
      w[2] = bf2f(e4.z) * sinv; w[3] = bf2f(e4.w) * sinv;
      *(f32x4*)(wrow + scol) = w;
    }
  }

  // ---- PV: wave wid covers d-subtile wid*16; A-frags from sc ----
  f32x4 oa0 = {}, oa1 = {};
  {
    const int qx = lr & 7;
    const unsigned short* vptr = vtg + ((size_t)bh * D + (wid << 4) + lr) * NSEQ + (lg << 3);
    #pragma unroll 2
    for (int t = 0; t < 16; ++t) {
      const int j0 = t << 6;
      const s16x8 pa0 = *(const s16x8*)(sc + lr * RS + ((((j0 >> 3) + lg) ^ qx) << 3));
      const s16x8 vf0 = *(const s16x8*)(vptr + j0);
      oa0 = __builtin_amdgcn_mfma_f32_16x16x32_bf16(pa0, vf0, oa0, 0, 0, 0);
      const s16x8 pa1 = *(const s16x8*)(sc + lr * RS + ((((j0 >> 3) + 4 + lg) ^ qx) << 3));
      const s16x8 vf1 = *(const s16x8*)(vptr + j0 + 32);
      oa1 = __builtin_amdgcn_mfma_f32_16x16x32_bf16(pa1, vf1, oa1, 0, 0, 0);
    }
  }

  // ---- aout (bf16): O rows q = lg*4+rg, col d = wid*16+lr ----
  {
    const int b = bh / H, hh = bh - b * H;
    const int d = (wid << 4) + lr;
    #pragma unroll
    for (int rg = 0; rg < 4; ++rg) {
      const int qi = (lg << 2) + rg;
      aout[((size_t)b * NSEQ + q0 + qi) * C + hh * D + d] =
          f2bf((oa0[rg] + oa1[rg]) * invs[qi]);
    }
  }
}

} // namespace

extern "C" void kernel_launch(void* const* d_in, const int* in_sizes, int n_in,
                              void* d_out, int out_size, void* d_ws, size_t ws_size,
                              hipStream_t stream) {
  const float* x      = (const float*)d_in[0];
  const float* qkv_w  = (const float*)d_in[1];
  const float* qkv_b  = (const float*)d_in[2];
  const float* proj_w = (const float*)d_in[3];
  const float* proj_b = (const float*)d_in[4];

  float* out   = (float*)d_out;                      // [8,1024,768] fp32
  float* attnw = out + (size_t)B * NSEQ * C;         // [8,12,1024,1024] fp32

  unsigned short* xb   = (unsigned short*)d_ws;             // [8192][768]
  unsigned short* wtq  = xb   + (size_t)8192 * 768;         // [2304][768]
  unsigned short* wtp  = wtq  + (size_t)2304 * 768;         // [768][768]
  unsigned short* qp   = wtp  + (size_t)768 * 768;          // [96][1024][64]
  unsigned short* kp   = qp   + QKV_ELEMS;
  unsigned short* vtp  = kp   + QKV_ELEMS;                  // [96][64][1024]
  unsigned short* wsao = vtp  + QKV_ELEMS;                  // [8192][768]

  cvt_x<<<1024, 256, 0, stream>>>(x, xb, (int)((size_t)8192 * 768 / 4));
  transp_cvt<<<dim3(N3 / 32, C / 32), 256, 0, stream>>>(qkv_w, wtq, C, N3);
  transp_cvt<<<dim3(C / 32, C / 32), 256, 0, stream>>>(proj_w, wtp, C, C);

  gemm_bf16<0><<<(N3 / 128) * (8192 / 128), 256, 0, stream>>>(
      xb, wtq, qkv_b, qp, kp, vtp, nullptr, N3, N3 / 128);

  attn_mfma<<<(NSEQ / 16) * (B * H), 256, 0, stream>>>(qp, kp, vtp, attnw, wsao);

  gemm_bf16<1><<<(C / 128) * (8192 / 128), 256, 0, stream>>>(
      wsao, wtp, proj_b, nullptr, nullptr, nullptr, out, C, C / 128);
}